// Round 1
// 117.651 us; speedup vs baseline: 1.0374x; 1.0374x over previous
//
#include <hip/hip_runtime.h>
#include <math.h>

#define EDIM 256
#define LDIM 1024
#define HDIM 8
#define DDIM 32

typedef __attribute__((ext_vector_type(8))) short short8;
typedef __attribute__((ext_vector_type(4))) float f32x4;
typedef __attribute__((ext_vector_type(4))) unsigned u32x4;

__device__ inline unsigned short bf16h(float x) {
    unsigned u = __float_as_uint(x);
    return (unsigned short)((u + 0x7fff + ((u >> 16) & 1)) >> 16);   // RNE
}
__device__ inline float bf16tof(unsigned short h) {
    return __uint_as_float(((unsigned)h) << 16);
}
// trunc-split: hi = leading 16 bits (exact subtraction), lo = RNE(residual).
// |x - hi - lo| <= 2^-17 |x|; cheaper than double-RNE split.
__device__ inline unsigned packsplit(float x) {
    unsigned u = __float_as_uint(x);
    float r = x - __uint_as_float(u & 0xffff0000u);
    return (u & 0xffff0000u) | (unsigned)bf16h(r);
}

// ---------------------------------------------------------------------------
// proj_kernel: dst(H,L,D) = X(L,E) @ W(E,E)^T, one GEMM per blockIdx.z.
// 32x32 tile, 2x2 micro, grid (32,8,3)=768 blocks (3 blocks/CU) for latency
// hiding. Software-pipelined: kb+1 global loads issued before kb compute.
// z==0 fuses coeff[h][n] = sum_d q[n,h,d]*Wr[h*32+d] (o-tile == one head).
// ---------------------------------------------------------------------------
__global__ __launch_bounds__(256) void proj_kernel(
    const float* __restrict__ Q, const float* __restrict__ Km, const float* __restrict__ V,
    const float* __restrict__ Wq, const float* __restrict__ Wk, const float* __restrict__ Wv,
    const float* __restrict__ Wr,
    float* __restrict__ qT, float* __restrict__ kT, float* __restrict__ vT,
    float* __restrict__ coeff)
{
    const int z = blockIdx.z;
    const float* __restrict__ X = (z == 0) ? Q : (z == 1) ? Km : V;
    const float* __restrict__ W = (z == 0) ? Wq : (z == 1) ? Wk : Wv;
    float* __restrict__ dst     = (z == 0) ? qT : (z == 1) ? kT : vT;

    const int n0 = blockIdx.x * 32;
    const int o0 = blockIdx.y * 32;       // one head (o0 = h*32)
    const int tid = threadIdx.x;
    const int tx = tid & 15, ty = tid >> 4;

    __shared__ float Xs[32][34];   // [e][n]
    __shared__ float Ws[32][34];   // [e][o]

    float acc[2][2] = {{0.f,0.f},{0.f,0.f}};

    const int sn  = tid >> 3;        // 0..31 tile row
    const int sc4 = (tid & 7) * 4;   // 0..28 k-chunk

    float4 xa = *(const float4*)(X + (n0 + sn) * EDIM + sc4);
    float4 wa = *(const float4*)(W + (o0 + sn) * EDIM + sc4);

    for (int kb = 0; kb < EDIM; kb += 32) {
        __syncthreads();   // previous compute done, LDS free
        Xs[sc4+0][sn]=xa.x; Xs[sc4+1][sn]=xa.y; Xs[sc4+2][sn]=xa.z; Xs[sc4+3][sn]=xa.w;
        Ws[sc4+0][sn]=wa.x; Ws[sc4+1][sn]=wa.y; Ws[sc4+2][sn]=wa.z; Ws[sc4+3][sn]=wa.w;
        float4 xn, wn;
        if (kb + 32 < EDIM) {
            xn = *(const float4*)(X + (n0 + sn) * EDIM + kb + 32 + sc4);
            wn = *(const float4*)(W + (o0 + sn) * EDIM + kb + 32 + sc4);
        }
        __syncthreads();   // staged
        #pragma unroll
        for (int e = 0; e < 32; ++e) {
            float2 x2 = *(const float2*)&Xs[e][ty*2];
            float2 w2 = *(const float2*)&Ws[e][tx*2];
            acc[0][0] += x2.x*w2.x; acc[0][1] += x2.x*w2.y;
            acc[1][0] += x2.y*w2.x; acc[1][1] += x2.y*w2.y;
        }
        xa = xn; wa = wn;
    }

    // write to (H, L, D): h = o0/32, d = tx*2
    const int h = o0 >> 5;
    #pragma unroll
    for (int i = 0; i < 2; ++i) {
        const int n = n0 + ty*2 + i;
        float2 r; r.x = acc[i][0]; r.y = acc[i][1];
        *(float2*)(dst + h*(LDIM*DDIM) + n*DDIM + tx*2) = r;
    }

    // fused coeff epilogue (q projection only): reduce over the 16 tx lanes
    if (z == 0) {
        const float wr0 = Wr[o0 + tx*2], wr1 = Wr[o0 + tx*2 + 1];
        #pragma unroll
        for (int i = 0; i < 2; ++i) {
            float c = acc[i][0]*wr0 + acc[i][1]*wr1;
            c += __shfl_xor(c, 1, 64);
            c += __shfl_xor(c, 2, 64);
            c += __shfl_xor(c, 4, 64);
            c += __shfl_xor(c, 8, 64);
            if (tx == 0) coeff[h*LDIM + n0 + ty*2 + i] = c;
        }
    }
}

// ---------------------------------------------------------------------------
// attn_kernel: flash attention. QK^T AND PV both on MFMA (split-bf16, 3 MFMAs
// per 16x16x32 step for fp32-class accuracy). P and V live in LDS as packed
// hi|lo u32 arrays laid out for direct A/B fragment reads (pitch 68 u32:
// rows 16B-aligned for ds_read_b128; read slot = (n + 2*quad) mod 8 -> even
// 8-slot spread = minimum-cycle b128; scalar writes 2-way = free).
// alpha-rescale is in-register (PV C/D rows == softmax state rows), which
// removes the alph[] array and the third barrier: 2 barriers per k-tile.
// Block: 64 q-rows, 4 waves. Grid (16, H, P). Writes unnormalized O + (m,l).
// ---------------------------------------------------------------------------
__global__ __launch_bounds__(256, 4) void attn_kernel(
    const float* __restrict__ qT, const float* __restrict__ kT, const float* __restrict__ vT,
    const float* __restrict__ coeff, const float* __restrict__ pos,
    float* __restrict__ Op, float* __restrict__ Mp, float* __restrict__ Lp, int nkt)
{
    const int h   = blockIdx.y;
    const int q0  = blockIdx.x * 64;
    const int p   = blockIdx.z;
    const int kt0 = p * nkt * 64;
    const int tid  = threadIdx.x;
    const int wave = tid >> 6;
    const int lane = tid & 63;
    const int n    = lane & 15;
    const int quad = lane >> 4;
    const int qs0  = wave * 16;

    __shared__ __align__(16) short khi[4*64*8];        // QK^T B-frags (hi)
    __shared__ __align__(16) short klo[4*64*8];        // QK^T B-frags (lo)
    __shared__ __align__(16) unsigned vs2[32][68];     // vs2[d][c] = hi|lo of V[c][d]
    __shared__ __align__(16) unsigned pA[64][68];      // pA[q][c]  = hi|lo of P[q][c]
    __shared__ float pk[64];

    // ---- Q fragments (A layout) — loaded once, trunc-split ----
    short8 qhi, qlo;
    {
        const float* qp = qT + (h*LDIM + q0 + qs0 + n) * DDIM + quad*8;
        float4 qa = *(const float4*)qp;
        float4 qb = *(const float4*)(qp + 4);
        float v[8] = {qa.x,qa.y,qa.z,qa.w, qb.x,qb.y,qb.z,qb.w};
        #pragma unroll
        for (int j = 0; j < 8; ++j) {
            unsigned u = __float_as_uint(v[j]);
            qhi[j] = (short)(u >> 16);
            qlo[j] = (short)bf16h(v[j] - __uint_as_float(u & 0xffff0000u));
        }
    }

    float pq[4], cq[4];
    #pragma unroll
    for (int i = 0; i < 4; ++i) {
        const int r = q0 + qs0 + 4*quad + i;
        pq[i] = pos[r];
        cq[i] = coeff[h*LDIM + r] * 0.0625f;
    }

    float m[4], l[4];
    #pragma unroll
    for (int i = 0; i < 4; ++i) { m[i] = -INFINITY; l[i] = 0.f; }

    // O accumulators in MFMA C/D layout: row = 4*quad+i, col d = dt*16 + n
    f32x4 of0 = {0.f,0.f,0.f,0.f}, of1 = {0.f,0.f,0.f,0.f};

    const int cS = tid >> 2;           // k-row 0..63
    const int dq = tid & 3;            // d-chunk 0..3 (8 floats each)
    const int lane2 = (cS & 15) | (dq << 4);
    const int gS = cS >> 4;

    // preload tile 0
    float4 k0c, k1c, v0c, v1c; float pkc = 0.f;
    {
        const float* kp = kT + (h*LDIM + kt0 + cS) * DDIM + dq*8;
        k0c = *(const float4*)kp; k1c = *(const float4*)(kp + 4);
        const float* vp = vT + (h*LDIM + kt0 + cS) * DDIM + dq*8;
        v0c = *(const float4*)vp; v1c = *(const float4*)(vp + 4);
        if (tid < 64) pkc = pos[kt0 + tid];
    }

    for (int t = 0; t < nkt; ++t) {
        __syncthreads();   // (A) prev tile's khi/klo + vs2 consumers done

        {   // stage K (split-bf16 B-frags), V (packed hi|lo, transposed), pk
            float kv[8] = {k0c.x,k0c.y,k0c.z,k0c.w, k1c.x,k1c.y,k1c.z,k1c.w};
            short8 hi8, lo8;
            #pragma unroll
            for (int j = 0; j < 8; ++j) {
                unsigned u = __float_as_uint(kv[j]);
                hi8[j] = (short)(u >> 16);
                lo8[j] = (short)bf16h(kv[j] - __uint_as_float(u & 0xffff0000u));
            }
            *((short8*)&khi[(gS*64 + lane2)*8]) = hi8;
            *((short8*)&klo[(gS*64 + lane2)*8]) = lo8;
            float vv[8] = {v0c.x,v0c.y,v0c.z,v0c.w, v1c.x,v1c.y,v1c.z,v1c.w};
            #pragma unroll
            for (int j = 0; j < 8; ++j)
                vs2[dq*8 + j][cS] = packsplit(vv[j]);
            if (tid < 64) pk[tid] = pkc;
        }

        // prefetch next tile (overlaps with compute below)
        float4 k0n, k1n, v0n, v1n; float pkn = 0.f;
        if (t + 1 < nkt) {
            const int kt = kt0 + (t+1) * 64;
            const float* kp = kT + (h*LDIM + kt + cS) * DDIM + dq*8;
            k0n = *(const float4*)kp; k1n = *(const float4*)(kp + 4);
            const float* vp = vT + (h*LDIM + kt + cS) * DDIM + dq*8;
            v0n = *(const float4*)vp; v1n = *(const float4*)(vp + 4);
            if (tid < 64) pkn = pos[kt + tid];
        }
        __syncthreads();   // (B) staging visible

        // ---- S = QK^T via 3-term split-bf16 MFMA, 4 col-tiles ----
        f32x4 Sf[4];
        #pragma unroll
        for (int t4 = 0; t4 < 4; ++t4) {
            short8 bhi = *((const short8*)&khi[(t4*64 + lane)*8]);
            short8 blo = *((const short8*)&klo[(t4*64 + lane)*8]);
            f32x4 acc = {0.f, 0.f, 0.f, 0.f};
            acc = __builtin_amdgcn_mfma_f32_16x16x32_bf16(qlo, bhi, acc, 0, 0, 0);
            acc = __builtin_amdgcn_mfma_f32_16x16x32_bf16(qhi, blo, acc, 0, 0, 0);
            acc = __builtin_amdgcn_mfma_f32_16x16x32_bf16(qhi, bhi, acc, 0, 0, 0);
            Sf[t4] = acc;
        }

        // ---- bias + online softmax (C/D layout: row 4*quad+i, col 16*t4+n) ----
        float ev[4][4];
        float rmax[4] = {-INFINITY, -INFINITY, -INFINITY, -INFINITY};
        #pragma unroll
        for (int t4 = 0; t4 < 4; ++t4) {
            const float pkt = pk[16*t4 + n];
            #pragma unroll
            for (int i = 0; i < 4; ++i) {
                float s = fmaf(Sf[t4][i], 0.0625f, cq[i] * __logf(fabsf(pq[i] - pkt) + 1.f));
                ev[t4][i] = s;
                rmax[i] = fmaxf(rmax[i], s);
            }
        }
        #pragma unroll
        for (int off = 1; off < 16; off <<= 1)
            #pragma unroll
            for (int i = 0; i < 4; ++i)
                rmax[i] = fmaxf(rmax[i], __shfl_xor(rmax[i], off, 64));

        float al[4], rsum[4];
        #pragma unroll
        for (int i = 0; i < 4; ++i) {
            const float mn = fmaxf(m[i], rmax[i]);
            al[i] = __expf(m[i] - mn);
            m[i] = mn;
            rsum[i] = 0.f;
        }
        // exp, accumulate row-sum, pack P to LDS in A-fragment-friendly layout.
        // pA rows [qs0, qs0+16) are wave-private: no barrier needed before PV.
        #pragma unroll
        for (int t4 = 0; t4 < 4; ++t4)
            #pragma unroll
            for (int i = 0; i < 4; ++i) {
                float e = __expf(ev[t4][i] - m[i]);
                rsum[i] += e;
                pA[qs0 + 4*quad + i][16*t4 + n] = packsplit(e);
            }
        #pragma unroll
        for (int off = 1; off < 16; off <<= 1)
            #pragma unroll
            for (int i = 0; i < 4; ++i)
                rsum[i] += __shfl_xor(rsum[i], off, 64);
        #pragma unroll
        for (int i = 0; i < 4; ++i) l[i] = l[i]*al[i] + rsum[i];

        // in-register O rescale: O rows (4*quad+i) match al[i] rows exactly
        #pragma unroll
        for (int i = 0; i < 4; ++i) { of0[i] *= al[i]; of1[i] *= al[i]; }

        // ---- PV on MFMA: O[q][d] += P[q][c] V[c][d], c in 2 chunks of 32 ----
        #pragma unroll
        for (int ch = 0; ch < 2; ++ch) {
            const unsigned* ap = &pA[qs0 + n][ch*32 + quad*8];
            u32x4 a0 = *(const u32x4*)ap;
            u32x4 a1 = *(const u32x4*)(ap + 4);
            short8 phi, plo;
            #pragma unroll
            for (int j = 0; j < 4; ++j) {
                phi[j]   = (short)(a0[j] >> 16);
                plo[j]   = (short)(a0[j] & 0xffffu);
                phi[j+4] = (short)(a1[j] >> 16);
                plo[j+4] = (short)(a1[j] & 0xffffu);
            }
            #pragma unroll
            for (int dt = 0; dt < 2; ++dt) {
                const unsigned* vp = &vs2[dt*16 + n][ch*32 + quad*8];
                u32x4 b0 = *(const u32x4*)vp;
                u32x4 b1 = *(const u32x4*)(vp + 4);
                short8 vhi, vlo;
                #pragma unroll
                for (int j = 0; j < 4; ++j) {
                    vhi[j]   = (short)(b0[j] >> 16);
                    vlo[j]   = (short)(b0[j] & 0xffffu);
                    vhi[j+4] = (short)(b1[j] >> 16);
                    vlo[j+4] = (short)(b1[j] & 0xffffu);
                }
                f32x4& of = dt ? of1 : of0;   // dt is unroll-constant: static
                of = __builtin_amdgcn_mfma_f32_16x16x32_bf16(plo, vhi, of, 0, 0, 0);
                of = __builtin_amdgcn_mfma_f32_16x16x32_bf16(phi, vlo, of, 0, 0, 0);
                of = __builtin_amdgcn_mfma_f32_16x16x32_bf16(phi, vhi, of, 0, 0, 0);
            }
        }

        k0c = k0n; k1c = k1n; v0c = v0n; v1c = v1n; pkc = pkn;
    }

    // epilogue: O is in C/D layout (row 4*quad+i, col dt*16+n)
    const int ph = p * HDIM + h;
    {
        const size_t base = ((size_t)ph * LDIM + q0 + qs0) * DDIM;
        #pragma unroll
        for (int i = 0; i < 4; ++i) {
            Op[base + (size_t)(4*quad + i)*DDIM + n]      = of0[i];
            Op[base + (size_t)(4*quad + i)*DDIM + 16 + n] = of1[i];
        }
    }
    if (n == 0) {
        #pragma unroll
        for (int i = 0; i < 4; ++i) {
            const int r = q0 + qs0 + 4*quad + i;
            Mp[ph*LDIM + r] = m[i];
            Lp[ph*LDIM + r] = l[i];
        }
    }
}

// ---------------------------------------------------------------------------
// combine_kernel: A(L,E) = normalized combine of P attention partials.
// 65536 threads (256 blocks), one float4 of A per thread. Mp/Lp loads are
// wave-broadcast (all 64 lanes share a row); Op loads coalesced per head.
// ---------------------------------------------------------------------------
__global__ __launch_bounds__(256) void combine_kernel(
    const float* __restrict__ Op, const float* __restrict__ Mp, const float* __restrict__ Lp,
    int P, float* __restrict__ A)
{
    const int idx = blockIdx.x * 256 + threadIdx.x;   // 0..65535
    const int n  = idx >> 6;          // row 0..1023
    const int e4 = (idx & 63) * 4;    // 0..252
    const int h  = e4 >> 5;
    const int d  = e4 & 31;

    float mv[8], lv[8];
    float mx = -INFINITY;
    #pragma unroll
    for (int p = 0; p < 8; ++p) if (p < P) {
        mv[p] = Mp[(p*HDIM + h)*LDIM + n];
        lv[p] = Lp[(p*HDIM + h)*LDIM + n];
        mx = fmaxf(mx, mv[p]);
    }
    float s = 0.f;
    #pragma unroll
    for (int p = 0; p < 8; ++p) if (p < P) {
        float a = __expf(mv[p] - mx);
        mv[p] = a;
        s += a * lv[p];
    }
    const float inv = 1.f / s;

    float4 x; x.x = x.y = x.z = x.w = 0.f;
    #pragma unroll
    for (int p = 0; p < 8; ++p) if (p < P) {
        const float sp = mv[p] * inv;
        float4 xp = *(const float4*)(Op + ((size_t)(p*HDIM + h)*LDIM + n)*DDIM + d);
        x.x += sp*xp.x; x.y += sp*xp.y; x.z += sp*xp.z; x.w += sp*xp.w;
    }
    *(float4*)(A + n*EDIM + e4) = x;
}

// ---------------------------------------------------------------------------
// outproj_kernel: out(L,E) = A(L,E) @ Wo(E,E)^T + bo. 32x32 tiles, 2x2 micro,
// grid (32,8)=256 blocks, software-pipelined like proj_kernel.
// ---------------------------------------------------------------------------
__global__ __launch_bounds__(256) void outproj_kernel(
    const float* __restrict__ A, const float* __restrict__ Wo,
    const float* __restrict__ bo, float* __restrict__ out)
{
    const int n0 = blockIdx.x * 32;
    const int o0 = blockIdx.y * 32;
    const int tid = threadIdx.x;
    const int tx = tid & 15, ty = tid >> 4;

    __shared__ float Xs[32][34];
    __shared__ float Ws[32][34];

    float acc[2][2] = {{0.f,0.f},{0.f,0.f}};

    const int sn  = tid >> 3;
    const int sc4 = (tid & 7) * 4;

    float4 xa = *(const float4*)(A  + (n0 + sn) * EDIM + sc4);
    float4 wa = *(const float4*)(Wo + (o0 + sn) * EDIM + sc4);

    for (int kb = 0; kb < EDIM; kb += 32) {
        __syncthreads();
        Xs[sc4+0][sn]=xa.x; Xs[sc4+1][sn]=xa.y; Xs[sc4+2][sn]=xa.z; Xs[sc4+3][sn]=xa.w;
        Ws[sc4+0][sn]=wa.x; Ws[sc4+1][sn]=wa.y; Ws[sc4+2][sn]=wa.z; Ws[sc4+3][sn]=wa.w;
        float4 xn, wn;
        if (kb + 32 < EDIM) {
            xn = *(const float4*)(A  + (n0 + sn) * EDIM + kb + 32 + sc4);
            wn = *(const float4*)(Wo + (o0 + sn) * EDIM + kb + 32 + sc4);
        }
        __syncthreads();
        #pragma unroll
        for (int e = 0; e < 32; ++e) {
            float2 x2 = *(const float2*)&Xs[e][ty*2];
            float2 w2 = *(const float2*)&Ws[e][tx*2];
            acc[0][0] += x2.x*w2.x; acc[0][1] += x2.x*w2.y;
            acc[1][0] += x2.y*w2.x; acc[1][1] += x2.y*w2.y;
        }
        xa = xn; wa = wn;
    }

    const int oo = o0 + tx*2;
    float2 bias = *(const float2*)(bo + oo);
    #pragma unroll
    for (int i = 0; i < 2; ++i) {
        const int nn = n0 + ty*2 + i;
        float2 r; r.x = acc[i][0] + bias.x; r.y = acc[i][1] + bias.y;
        *(float2*)(out + nn*EDIM + oo) = r;
    }
}

// ---------------------------------------------------------------------------
extern "C" void kernel_launch(void* const* d_in, const int* in_sizes, int n_in,
                              void* d_out, int out_size, void* d_ws, size_t ws_size,
                              hipStream_t stream) {
    const float* V   = (const float*)d_in[0];
    const float* K   = (const float*)d_in[1];
    const float* Q   = (const float*)d_in[2];
    const float* pos = (const float*)d_in[3];
    const float* Wq  = (const float*)d_in[4];
    const float* Wk  = (const float*)d_in[5];
    const float* Wv  = (const float*)d_in[6];
    const float* Wr  = (const float*)d_in[7];
    const float* Wo  = (const float*)d_in[8];
    const float* bo  = (const float*)d_in[9];
    float* out = (float*)d_out;
    float* ws  = (float*)d_ws;

    auto need = [](int P) -> size_t {
        return (size_t)(794624 + P*278528) * 4;
    };
    int P = 2;
    if (ws_size >= need(8)) P = 8;
    else if (ws_size >= need(4)) P = 4;

    float* qT    = ws;                      // also reused as A after attn
    float* kT    = ws + 262144;
    float* vT    = ws + 524288;
    float* coeff = ws + 786432;
    float* Op    = ws + 794624;
    float* Mp    = Op + (size_t)P * 262144;
    float* Lp    = Mp + (size_t)P * 8192;
    float* A     = qT;                      // qT dead after attn_kernel

    proj_kernel   <<<dim3(32, 8, 3), 256, 0, stream>>>(Q, K, V, Wq, Wk, Wv, Wr, qT, kT, vT, coeff);
    attn_kernel   <<<dim3(16, 8, P), 256, 0, stream>>>(qT, kT, vT, coeff, pos, Op, Mp, Lp, 16 / P);
    combine_kernel<<<dim3(256),      256, 0, stream>>>(Op, Mp, Lp, P, A);
    outproj_kernel<<<dim3(32, 8),    256, 0, stream>>>(A, Wo, bo, out);
}

// Round 2
// 106.783 us; speedup vs baseline: 1.1429x; 1.1018x over previous
//
#include <hip/hip_runtime.h>
#include <math.h>

#define EDIM 256
#define LDIM 1024
#define HDIM 8
#define DDIM 32

typedef __attribute__((ext_vector_type(8))) short short8;
typedef __attribute__((ext_vector_type(4))) float f32x4;
typedef __attribute__((ext_vector_type(4))) unsigned u32x4;

__device__ inline unsigned short bf16h(float x) {
    unsigned u = __float_as_uint(x);
    return (unsigned short)((u + 0x7fff + ((u >> 16) & 1)) >> 16);   // RNE
}
__device__ inline float bf16tof(unsigned short h) {
    return __uint_as_float(((unsigned)h) << 16);
}
// trunc-split: hi = leading 16 bits (exact), lo = RNE(residual). err <= 2^-17|x|
__device__ inline unsigned packsplit(float x) {
    unsigned u = __float_as_uint(x);
    float r = x - __uint_as_float(u & 0xffff0000u);
    return (u & 0xffff0000u) | (unsigned)bf16h(r);
}
// RNE-split: hi = RNE-bf16(x), lo = RNE(x - hi). err <= 2^-18|x| (2x tighter)
__device__ inline unsigned packsplit_rne(float x) {
    unsigned short h = bf16h(x);
    float r = x - bf16tof(h);
    return ((unsigned)h << 16) | (unsigned)bf16h(r);
}

// ---------------------------------------------------------------------------
// proj_kernel (MFMA): dst(H,L,D) = X(L,E) @ W(E,E)^T per blockIdx.z, output
// PACKED as hi|lo u32 (consumers unpack with shifts only). 32x32 tile, 4
// waves x one 16x16 MFMA frag, BK=64 (2 K-slices/iter), split-bf16 3-term.
// Frag LDS is linear lane*16B (khi-style) => conflict-free ds_read_b128.
// z==0 fuses coeff[h][n] = sum_d q[n,h,d]*Wr[h*32+d].
// ---------------------------------------------------------------------------
__global__ __launch_bounds__(256) void proj_kernel(
    const float* __restrict__ Q, const float* __restrict__ Km, const float* __restrict__ V,
    const float* __restrict__ Wq, const float* __restrict__ Wk, const float* __restrict__ Wv,
    const float* __restrict__ Wr,
    unsigned* __restrict__ qT, unsigned* __restrict__ kT, unsigned* __restrict__ vT,
    float* __restrict__ coeff)
{
    const int z = blockIdx.z;
    const float* __restrict__ X = (z == 0) ? Q : (z == 1) ? Km : V;
    const float* __restrict__ W = (z == 0) ? Wq : (z == 1) ? Wk : Wv;
    unsigned* __restrict__ dst  = (z == 0) ? qT : (z == 1) ? kT : vT;

    const int n0 = blockIdx.x * 32;
    const int o0 = blockIdx.y * 32;   // one head: o0 = h*32
    const int tid = threadIdx.x;
    const int wave = tid >> 6, lane = tid & 63;
    const int n = lane & 15, quad = lane >> 4;
    const int rh = wave & 1, oh = wave >> 1;   // wave's row-half / col-half

    // staging role: K-slice s (32 wide), row r (0..31), k-quad qd (8 elems)
    const int s    = tid >> 7;
    const int r    = (tid >> 2) & 31;
    const int qd   = tid & 3;
    const int half = r >> 4;
    const int fl8  = ((r & 15) | (qd << 4)) * 8;   // frag-lane * 8

    __shared__ short Xhi[2][2][512], Xlo[2][2][512];   // [slice][row-half][lane*8]
    __shared__ short Whi[2][2][512], Wlo[2][2][512];
    __shared__ float cpart[2][2][16];

    const float* xp = X + (n0 + r) * EDIM + s * 32 + qd * 8;
    const float* wp = W + (o0 + r) * EDIM + s * 32 + qd * 8;

    float4 xa0 = *(const float4*)xp, xa1 = *(const float4*)(xp + 4);
    float4 wa0 = *(const float4*)wp, wa1 = *(const float4*)(wp + 4);

    f32x4 acc = {0.f, 0.f, 0.f, 0.f};

    for (int kb = 0; kb < EDIM; kb += 64) {
        __syncthreads();   // previous compute done, LDS free
        {
            float xv[8] = {xa0.x,xa0.y,xa0.z,xa0.w, xa1.x,xa1.y,xa1.z,xa1.w};
            float wv[8] = {wa0.x,wa0.y,wa0.z,wa0.w, wa1.x,wa1.y,wa1.z,wa1.w};
            short8 xh, xl, wh, wl;
            #pragma unroll
            for (int j = 0; j < 8; ++j) {
                unsigned px = packsplit_rne(xv[j]);
                unsigned pw = packsplit_rne(wv[j]);
                xh[j] = (short)(px >> 16); xl[j] = (short)(px & 0xffffu);
                wh[j] = (short)(pw >> 16); wl[j] = (short)(pw & 0xffffu);
            }
            *(short8*)&Xhi[s][half][fl8] = xh;
            *(short8*)&Xlo[s][half][fl8] = xl;
            *(short8*)&Whi[s][half][fl8] = wh;
            *(short8*)&Wlo[s][half][fl8] = wl;
        }
        float4 xn0, xn1, wn0, wn1;
        if (kb + 64 < EDIM) {
            xn0 = *(const float4*)(xp + kb + 64); xn1 = *(const float4*)(xp + kb + 68);
            wn0 = *(const float4*)(wp + kb + 64); wn1 = *(const float4*)(wp + kb + 68);
        }
        __syncthreads();   // staged
        #pragma unroll
        for (int ss = 0; ss < 2; ++ss) {
            short8 ah = *(const short8*)&Xhi[ss][rh][lane*8];
            short8 al = *(const short8*)&Xlo[ss][rh][lane*8];
            short8 bh = *(const short8*)&Whi[ss][oh][lane*8];
            short8 bl = *(const short8*)&Wlo[ss][oh][lane*8];
            acc = __builtin_amdgcn_mfma_f32_16x16x32_bf16(al, bh, acc, 0, 0, 0);
            acc = __builtin_amdgcn_mfma_f32_16x16x32_bf16(ah, bl, acc, 0, 0, 0);
            acc = __builtin_amdgcn_mfma_f32_16x16x32_bf16(ah, bh, acc, 0, 0, 0);
        }
        xa0 = xn0; xa1 = xn1; wa0 = wn0; wa1 = wn1;
    }

    // epilogue: D layout row = rh*16 + 4*quad + i, col = oh*16 + n. Packed out.
    const int h  = o0 >> 5;
    const int og = oh * 16 + n;
    #pragma unroll
    for (int i = 0; i < 4; ++i) {
        const int row = rh * 16 + 4 * quad + i;
        dst[(h * LDIM + n0 + row) * DDIM + og] = packsplit_rne(acc[i]);
    }

    if (z == 0) {   // coeff[h][n] = sum over d (all 32 cols = 2 waves x 16 lanes)
        const float wr = Wr[o0 + og];
        #pragma unroll
        for (int i = 0; i < 4; ++i) {
            float c = acc[i] * wr;
            c += __shfl_xor(c, 1, 64);
            c += __shfl_xor(c, 2, 64);
            c += __shfl_xor(c, 4, 64);
            c += __shfl_xor(c, 8, 64);
            if (n == 0) cpart[rh][oh][4*quad + i] = c;
        }
        __syncthreads();
        if (tid < 32)
            coeff[h * LDIM + n0 + tid] = cpart[tid >> 4][0][tid & 15]
                                       + cpart[tid >> 4][1][tid & 15];
    }
}

// ---------------------------------------------------------------------------
// attn_kernel: flash attention, QK^T and PV on MFMA (split-bf16 3-term).
// q/k/v arrive PACKED (hi|lo u32): K staging = shifts only, V staging = pure
// u32 copy, Q frag = shifts only. 2 barriers per k-tile; in-register alpha
// rescale. Block: 64 q-rows, 4 waves. Grid (16, H, P).
// ---------------------------------------------------------------------------
__global__ __launch_bounds__(256, 4) void attn_kernel(
    const unsigned* __restrict__ qT, const unsigned* __restrict__ kT, const unsigned* __restrict__ vT,
    const float* __restrict__ coeff, const float* __restrict__ pos,
    float* __restrict__ Op, float* __restrict__ Mp, float* __restrict__ Lp, int nkt)
{
    const int h   = blockIdx.y;
    const int q0  = blockIdx.x * 64;
    const int p   = blockIdx.z;
    const int kt0 = p * nkt * 64;
    const int tid  = threadIdx.x;
    const int wave = tid >> 6;
    const int lane = tid & 63;
    const int n    = lane & 15;
    const int quad = lane >> 4;
    const int qs0  = wave * 16;

    __shared__ __align__(16) short khi[4*64*8];        // QK^T B-frags (hi)
    __shared__ __align__(16) short klo[4*64*8];        // QK^T B-frags (lo)
    __shared__ __align__(16) unsigned vs2[32][68];     // vs2[d][c] = packed V[c][d]
    __shared__ __align__(16) unsigned pA[64][68];      // pA[q][c]  = packed P[q][c]
    __shared__ float pk[64];

    // ---- Q fragments (A layout) — packed input, shift-unpack only ----
    short8 qhi, qlo;
    {
        const unsigned* qp = qT + (h*LDIM + q0 + qs0 + n) * DDIM + quad*8;
        u32x4 a0 = *(const u32x4*)qp;
        u32x4 a1 = *(const u32x4*)(qp + 4);
        #pragma unroll
        for (int j = 0; j < 4; ++j) {
            qhi[j]   = (short)(a0[j] >> 16);  qlo[j]   = (short)(a0[j] & 0xffffu);
            qhi[j+4] = (short)(a1[j] >> 16);  qlo[j+4] = (short)(a1[j] & 0xffffu);
        }
    }

    float pq[4], cq[4];
    #pragma unroll
    for (int i = 0; i < 4; ++i) {
        const int r = q0 + qs0 + 4*quad + i;
        pq[i] = pos[r];
        cq[i] = coeff[h*LDIM + r] * 0.0625f;
    }

    float m[4], l[4];
    #pragma unroll
    for (int i = 0; i < 4; ++i) { m[i] = -INFINITY; l[i] = 0.f; }

    // O accumulators in MFMA C/D layout: row = 4*quad+i, col d = dt*16 + n
    f32x4 of0 = {0.f,0.f,0.f,0.f}, of1 = {0.f,0.f,0.f,0.f};

    const int cS = tid >> 2;           // k-row 0..63
    const int dq = tid & 3;            // d-chunk 0..3 (8 elems each)
    const int lane2 = (cS & 15) | (dq << 4);
    const int gS = cS >> 4;

    // preload tile 0 (packed u32)
    u32x4 k0c, k1c, v0c, v1c; float pkc = 0.f;
    {
        const unsigned* kp = kT + (h*LDIM + kt0 + cS) * DDIM + dq*8;
        k0c = *(const u32x4*)kp; k1c = *(const u32x4*)(kp + 4);
        const unsigned* vp = vT + (h*LDIM + kt0 + cS) * DDIM + dq*8;
        v0c = *(const u32x4*)vp; v1c = *(const u32x4*)(vp + 4);
        if (tid < 64) pkc = pos[kt0 + tid];
    }

    for (int t = 0; t < nkt; ++t) {
        __syncthreads();   // (A) prev tile's consumers done

        {   // stage K (shift-split to B-frags), V (raw packed copy), pk
            short8 hi8, lo8;
            #pragma unroll
            for (int j = 0; j < 4; ++j) {
                hi8[j]   = (short)(k0c[j] >> 16);  lo8[j]   = (short)(k0c[j] & 0xffffu);
                hi8[j+4] = (short)(k1c[j] >> 16);  lo8[j+4] = (short)(k1c[j] & 0xffffu);
            }
            *((short8*)&khi[(gS*64 + lane2)*8]) = hi8;
            *((short8*)&klo[(gS*64 + lane2)*8]) = lo8;
            #pragma unroll
            for (int j = 0; j < 4; ++j) {
                vs2[dq*8 + j][cS]     = v0c[j];
                vs2[dq*8 + j + 4][cS] = v1c[j];
            }
            if (tid < 64) pk[tid] = pkc;
        }

        // prefetch next tile (overlaps with compute below)
        u32x4 k0n, k1n, v0n, v1n; float pkn = 0.f;
        if (t + 1 < nkt) {
            const int kt = kt0 + (t+1) * 64;
            const unsigned* kp = kT + (h*LDIM + kt + cS) * DDIM + dq*8;
            k0n = *(const u32x4*)kp; k1n = *(const u32x4*)(kp + 4);
            const unsigned* vp = vT + (h*LDIM + kt + cS) * DDIM + dq*8;
            v0n = *(const u32x4*)vp; v1n = *(const u32x4*)(vp + 4);
            if (tid < 64) pkn = pos[kt + tid];
        }
        __syncthreads();   // (B) staging visible

        // ---- S = QK^T via 3-term split-bf16 MFMA, 4 col-tiles ----
        f32x4 Sf[4];
        #pragma unroll
        for (int t4 = 0; t4 < 4; ++t4) {
            short8 bhi = *((const short8*)&khi[(t4*64 + lane)*8]);
            short8 blo = *((const short8*)&klo[(t4*64 + lane)*8]);
            f32x4 acc = {0.f, 0.f, 0.f, 0.f};
            acc = __builtin_amdgcn_mfma_f32_16x16x32_bf16(qlo, bhi, acc, 0, 0, 0);
            acc = __builtin_amdgcn_mfma_f32_16x16x32_bf16(qhi, blo, acc, 0, 0, 0);
            acc = __builtin_amdgcn_mfma_f32_16x16x32_bf16(qhi, bhi, acc, 0, 0, 0);
            Sf[t4] = acc;
        }

        // ---- bias + online softmax (C/D layout: row 4*quad+i, col 16*t4+n) ----
        float ev[4][4];
        float rmax[4] = {-INFINITY, -INFINITY, -INFINITY, -INFINITY};
        #pragma unroll
        for (int t4 = 0; t4 < 4; ++t4) {
            const float pkt = pk[16*t4 + n];
            #pragma unroll
            for (int i = 0; i < 4; ++i) {
                float s = fmaf(Sf[t4][i], 0.0625f, cq[i] * __logf(fabsf(pq[i] - pkt) + 1.f));
                ev[t4][i] = s;
                rmax[i] = fmaxf(rmax[i], s);
            }
        }
        #pragma unroll
        for (int off = 1; off < 16; off <<= 1)
            #pragma unroll
            for (int i = 0; i < 4; ++i)
                rmax[i] = fmaxf(rmax[i], __shfl_xor(rmax[i], off, 64));

        float al[4], rsum[4];
        #pragma unroll
        for (int i = 0; i < 4; ++i) {
            const float mn = fmaxf(m[i], rmax[i]);
            al[i] = __expf(m[i] - mn);
            m[i] = mn;
            rsum[i] = 0.f;
        }
        // exp, row-sum, pack P into LDS (wave-private rows: no barrier needed)
        #pragma unroll
        for (int t4 = 0; t4 < 4; ++t4)
            #pragma unroll
            for (int i = 0; i < 4; ++i) {
                float e = __expf(ev[t4][i] - m[i]);
                rsum[i] += e;
                pA[qs0 + 4*quad + i][16*t4 + n] = packsplit(e);
            }
        #pragma unroll
        for (int off = 1; off < 16; off <<= 1)
            #pragma unroll
            for (int i = 0; i < 4; ++i)
                rsum[i] += __shfl_xor(rsum[i], off, 64);
        #pragma unroll
        for (int i = 0; i < 4; ++i) l[i] = l[i]*al[i] + rsum[i];

        // in-register O rescale: O rows (4*quad+i) match al[i] rows exactly
        #pragma unroll
        for (int i = 0; i < 4; ++i) { of0[i] *= al[i]; of1[i] *= al[i]; }

        // ---- PV on MFMA: O[q][d] += P[q][c] V[c][d], c in 2 chunks of 32 ----
        #pragma unroll
        for (int ch = 0; ch < 2; ++ch) {
            const unsigned* ap = &pA[qs0 + n][ch*32 + quad*8];
            u32x4 a0 = *(const u32x4*)ap;
            u32x4 a1 = *(const u32x4*)(ap + 4);
            short8 phi, plo;
            #pragma unroll
            for (int j = 0; j < 4; ++j) {
                phi[j]   = (short)(a0[j] >> 16);
                plo[j]   = (short)(a0[j] & 0xffffu);
                phi[j+4] = (short)(a1[j] >> 16);
                plo[j+4] = (short)(a1[j] & 0xffffu);
            }
            #pragma unroll
            for (int dt = 0; dt < 2; ++dt) {
                const unsigned* vp = &vs2[dt*16 + n][ch*32 + quad*8];
                u32x4 b0 = *(const u32x4*)vp;
                u32x4 b1 = *(const u32x4*)(vp + 4);
                short8 vhi, vlo;
                #pragma unroll
                for (int j = 0; j < 4; ++j) {
                    vhi[j]   = (short)(b0[j] >> 16);
                    vlo[j]   = (short)(b0[j] & 0xffffu);
                    vhi[j+4] = (short)(b1[j] >> 16);
                    vlo[j+4] = (short)(b1[j] & 0xffffu);
                }
                f32x4& of = dt ? of1 : of0;   // dt is unroll-constant: static
                of = __builtin_amdgcn_mfma_f32_16x16x32_bf16(plo, vhi, of, 0, 0, 0);
                of = __builtin_amdgcn_mfma_f32_16x16x32_bf16(phi, vlo, of, 0, 0, 0);
                of = __builtin_amdgcn_mfma_f32_16x16x32_bf16(phi, vhi, of, 0, 0, 0);
            }
        }

        k0c = k0n; k1c = k1n; v0c = v0n; v1c = v1n; pkc = pkn;
    }

    // epilogue: O is in C/D layout (row 4*quad+i, col dt*16+n)
    const int ph = p * HDIM + h;
    {
        const size_t base = ((size_t)ph * LDIM + q0 + qs0) * DDIM;
        #pragma unroll
        for (int i = 0; i < 4; ++i) {
            Op[base + (size_t)(4*quad + i)*DDIM + n]      = of0[i];
            Op[base + (size_t)(4*quad + i)*DDIM + 16 + n] = of1[i];
        }
    }
    if (n == 0) {
        #pragma unroll
        for (int i = 0; i < 4; ++i) {
            const int r = q0 + qs0 + 4*quad + i;
            Mp[ph*LDIM + r] = m[i];
            Lp[ph*LDIM + r] = l[i];
        }
    }
}

// ---------------------------------------------------------------------------
// combine_kernel: A(L,E) = normalized combine of P attention partials.
// ---------------------------------------------------------------------------
__global__ __launch_bounds__(256) void combine_kernel(
    const float* __restrict__ Op, const float* __restrict__ Mp, const float* __restrict__ Lp,
    int P, float* __restrict__ A)
{
    const int idx = blockIdx.x * 256 + threadIdx.x;   // 0..65535
    const int n  = idx >> 6;          // row 0..1023
    const int e4 = (idx & 63) * 4;    // 0..252
    const int h  = e4 >> 5;
    const int d  = e4 & 31;

    float mv[8], lv[8];
    float mx = -INFINITY;
    #pragma unroll
    for (int p = 0; p < 8; ++p) if (p < P) {
        mv[p] = Mp[(p*HDIM + h)*LDIM + n];
        lv[p] = Lp[(p*HDIM + h)*LDIM + n];
        mx = fmaxf(mx, mv[p]);
    }
    float s = 0.f;
    #pragma unroll
    for (int p = 0; p < 8; ++p) if (p < P) {
        float a = __expf(mv[p] - mx);
        mv[p] = a;
        s += a * lv[p];
    }
    const float inv = 1.f / s;

    float4 x; x.x = x.y = x.z = x.w = 0.f;
    #pragma unroll
    for (int p = 0; p < 8; ++p) if (p < P) {
        const float sp = mv[p] * inv;
        float4 xp = *(const float4*)(Op + ((size_t)(p*HDIM + h)*LDIM + n)*DDIM + d);
        x.x += sp*xp.x; x.y += sp*xp.y; x.z += sp*xp.z; x.w += sp*xp.w;
    }
    *(float4*)(A + n*EDIM + e4) = x;
}

// ---------------------------------------------------------------------------
// outproj_kernel (MFMA): out(L,E) = A(L,E) @ Wo(E,E)^T + bo. Same template as
// proj_kernel (fp32 in-flow RNE split, 3-term), fp32 output + bias epilogue.
// ---------------------------------------------------------------------------
__global__ __launch_bounds__(256) void outproj_kernel(
    const float* __restrict__ A, const float* __restrict__ Wo,
    const float* __restrict__ bo, float* __restrict__ out)
{
    const int n0 = blockIdx.x * 32;
    const int o0 = blockIdx.y * 32;
    const int tid = threadIdx.x;
    const int wave = tid >> 6, lane = tid & 63;
    const int n = lane & 15, quad = lane >> 4;
    const int rh = wave & 1, oh = wave >> 1;

    const int s    = tid >> 7;
    const int r    = (tid >> 2) & 31;
    const int qd   = tid & 3;
    const int half = r >> 4;
    const int fl8  = ((r & 15) | (qd << 4)) * 8;

    __shared__ short Xhi[2][2][512], Xlo[2][2][512];
    __shared__ short Whi[2][2][512], Wlo[2][2][512];

    const float* xp = A  + (n0 + r) * EDIM + s * 32 + qd * 8;
    const float* wp = Wo + (o0 + r) * EDIM + s * 32 + qd * 8;

    float4 xa0 = *(const float4*)xp, xa1 = *(const float4*)(xp + 4);
    float4 wa0 = *(const float4*)wp, wa1 = *(const float4*)(wp + 4);

    f32x4 acc = {0.f, 0.f, 0.f, 0.f};

    for (int kb = 0; kb < EDIM; kb += 64) {
        __syncthreads();
        {
            float xv[8] = {xa0.x,xa0.y,xa0.z,xa0.w, xa1.x,xa1.y,xa1.z,xa1.w};
            float wv[8] = {wa0.x,wa0.y,wa0.z,wa0.w, wa1.x,wa1.y,wa1.z,wa1.w};
            short8 xh, xl, wh, wl;
            #pragma unroll
            for (int j = 0; j < 8; ++j) {
                unsigned px = packsplit_rne(xv[j]);
                unsigned pw = packsplit_rne(wv[j]);
                xh[j] = (short)(px >> 16); xl[j] = (short)(px & 0xffffu);
                wh[j] = (short)(pw >> 16); wl[j] = (short)(pw & 0xffffu);
            }
            *(short8*)&Xhi[s][half][fl8] = xh;
            *(short8*)&Xlo[s][half][fl8] = xl;
            *(short8*)&Whi[s][half][fl8] = wh;
            *(short8*)&Wlo[s][half][fl8] = wl;
        }
        float4 xn0, xn1, wn0, wn1;
        if (kb + 64 < EDIM) {
            xn0 = *(const float4*)(xp + kb + 64); xn1 = *(const float4*)(xp + kb + 68);
            wn0 = *(const float4*)(wp + kb + 64); wn1 = *(const float4*)(wp + kb + 68);
        }
        __syncthreads();
        #pragma unroll
        for (int ss = 0; ss < 2; ++ss) {
            short8 ah = *(const short8*)&Xhi[ss][rh][lane*8];
            short8 al = *(const short8*)&Xlo[ss][rh][lane*8];
            short8 bh = *(const short8*)&Whi[ss][oh][lane*8];
            short8 bl = *(const short8*)&Wlo[ss][oh][lane*8];
            acc = __builtin_amdgcn_mfma_f32_16x16x32_bf16(al, bh, acc, 0, 0, 0);
            acc = __builtin_amdgcn_mfma_f32_16x16x32_bf16(ah, bl, acc, 0, 0, 0);
            acc = __builtin_amdgcn_mfma_f32_16x16x32_bf16(ah, bh, acc, 0, 0, 0);
        }
        xa0 = xn0; xa1 = xn1; wa0 = wn0; wa1 = wn1;
    }

    const int og = o0 + oh*16 + n;
    const float b = bo[og];
    #pragma unroll
    for (int i = 0; i < 4; ++i) {
        const int row = n0 + rh*16 + 4*quad + i;
        out[row * EDIM + og] = acc[i] + b;
    }
}

// ---------------------------------------------------------------------------
extern "C" void kernel_launch(void* const* d_in, const int* in_sizes, int n_in,
                              void* d_out, int out_size, void* d_ws, size_t ws_size,
                              hipStream_t stream) {
    const float* V   = (const float*)d_in[0];
    const float* K   = (const float*)d_in[1];
    const float* Q   = (const float*)d_in[2];
    const float* pos = (const float*)d_in[3];
    const float* Wq  = (const float*)d_in[4];
    const float* Wk  = (const float*)d_in[5];
    const float* Wv  = (const float*)d_in[6];
    const float* Wr  = (const float*)d_in[7];
    const float* Wo  = (const float*)d_in[8];
    const float* bo  = (const float*)d_in[9];
    float* out = (float*)d_out;
    float* ws  = (float*)d_ws;

    auto need = [](int P) -> size_t {
        return (size_t)(794624 + P*278528) * 4;
    };
    int P = 2;
    if (ws_size >= need(8)) P = 8;
    else if (ws_size >= need(4)) P = 4;

    unsigned* qT = (unsigned*)ws;           // packed hi|lo; reused as A later
    unsigned* kT = (unsigned*)(ws + 262144);
    unsigned* vT = (unsigned*)(ws + 524288);
    float* coeff = ws + 786432;
    float* Op    = ws + 794624;
    float* Mp    = Op + (size_t)P * 262144;
    float* Lp    = Mp + (size_t)P * 8192;
    float* A     = ws;                      // qT dead after attn_kernel

    proj_kernel   <<<dim3(32, 8, 3), 256, 0, stream>>>(Q, K, V, Wq, Wk, Wv, Wr, qT, kT, vT, coeff);
    attn_kernel   <<<dim3(16, 8, P), 256, 0, stream>>>(qT, kT, vT, coeff, pos, Op, Mp, Lp, 16 / P);
    combine_kernel<<<dim3(256),      256, 0, stream>>>(Op, Mp, Lp, P, A);
    outproj_kernel<<<dim3(32, 8),    256, 0, stream>>>(A, Wo, bo, out);
}